// Round 6
// baseline (111.902 us; speedup 1.0000x reference)
//
#include <hip/hip_runtime.h>

typedef unsigned long long u64;
typedef unsigned short u16;

#define HH 384
#define WW 384
#define BB 8
#define CC 3
#define NMASK (BB*CC)        // 24
#define PLANE (HH*WW)        // 147456
#define NW 6                 // 384 rows = 6 x 64-bit words
#define GROUPS 24            // row groups of 16
#define ROWS_PG 16
#define INF_F 1.0e6f
#define NBLK (GROUPS*BB*CC)  // 576

// ---------------------------------------------------------------------------
// ws layout:
//   u64      bm[BB][CC][NW][WW]     column seed bitmasks (442368 B)
//   float    out4f[NMASK][GROUPS][4]  per-(b,c,g): {sum_fg, sum_bg, max_fg, max_bg}
//   unsigned counter                last-block-done ticket (zeroed by buildbm)
// loss = sum_m S_bg/max_bg - S_fg/max_fg  (divide-after-sum; ~1e-7 rel vs 4.6e-4 thr)
// mask non-empty <=> max_bg <= 1000 (real EDT max < 542; empty-set dists >= 1e6)
// ---------------------------------------------------------------------------

// Grid (BB, NW, 4): thread j builds a 16-bit partial of the 64-row bitmask word
// for its column, all 3 classes (u16 stores into the u64 array, little-endian
// -> no atomics, no zero-init). Block (0,0,0) also zeroes the ticket counter.
__global__ __launch_bounds__(WW) void buildbm(const int* __restrict__ targets,
                                              u16* __restrict__ bm16,
                                              unsigned* __restrict__ counter) {
    int b = blockIdx.x, w = blockIdx.y, q = blockIdx.z;
    int j = threadIdx.x;
    if (b == 0 && w == 0 && q == 0 && j == 0) *counter = 0u;
    const int* tg = targets + (size_t)b * PLANE + (w * 64 + q * 16) * WW + j;
    unsigned m0 = 0, m1 = 0, m2 = 0;
#pragma unroll
    for (int r = 0; r < 16; ++r) {
        int t = tg[r * WW];
        unsigned bit = 1u << r;
        m0 |= (t == 0) ? bit : 0u;
        m1 |= (t == 1) ? bit : 0u;
        m2 |= (t == 2) ? bit : 0u;
    }
    size_t base = (((size_t)b * CC) * NW + w) * WW + j;          // c = 0
    bm16[base * 4 + q] = (u16)m0;
    bm16[(base + (size_t)NW * WW) * 4 + q] = (u16)m1;
    bm16[(base + 2 * (size_t)NW * WW) * 4 + q] = (u16)m2;
}

// Grid (GROUPS, BB, CC): block = 16 rows x 384 cols for one class's fg/bg.
// Phase A: thread j loads its column's 6 bitmask words once, precomputes
// cross-word prev/next anchors, emits all 16 rows' exact column distances
// (bit-identical to the reference scan) squared into LDS. ONE barrier.
// Phase B: per row, softmax(logits) weight + expanding-ring row-EDT
// (safe prune: rr >= mn => candidate = rr + g2 >= mn), register accumulation.
// Epilogue: block reduce -> agent-scope stores; last arriving block reduces
// the 576 partials to the scalar loss (release/acquire via ticket counter).
__global__ __launch_bounds__(WW) void edt16f(const u64* __restrict__ bm,
                                             const float* __restrict__ logits,
                                             float* __restrict__ out4f,
                                             unsigned* __restrict__ counter,
                                             float* __restrict__ out) {
    __shared__ float g2all[ROWS_PG][2][WW];   // 49152 B
    __shared__ float red[4][WW / 64];
    __shared__ float contrib[NMASK];
    __shared__ unsigned sticket;
    int g = blockIdx.x, b = blockIdx.y, c = blockIdx.z;
    int j = threadIdx.x;
    int i0 = g * ROWS_PG;
    int w = i0 >> 6;                          // all 16 rows live in this word

    u64 wb[NW];
#pragma unroll
    for (int wq = 0; wq < NW; ++wq)
        wb[wq] = bm[(((size_t)b * CC + c) * NW + wq) * WW + j];

    // anchors: P* = highest seed index in words < w, N* = lowest in words > w
    int Pbg = -1, Pfg = -1, Nbg = -1, Nfg = -1;
#pragma unroll
    for (int wq = 0; wq < NW; ++wq) {
        u64 bw = wb[wq], fw = ~wb[wq];
        if (wq < w) {
            if (bw) Pbg = wq * 64 + 63 - __builtin_clzll(bw | 1ull);
            if (fw) Pfg = wq * 64 + 63 - __builtin_clzll(fw | 1ull);
        }
    }
#pragma unroll
    for (int wq = NW - 1; wq >= 0; --wq) {
        u64 bw = wb[wq], fw = ~wb[wq];
        if (wq > w) {
            if (bw) Nbg = wq * 64 + (int)__builtin_ctzll(bw | 0x8000000000000000ull);
            if (fw) Nfg = wq * 64 + (int)__builtin_ctzll(fw | 0x8000000000000000ull);
        }
    }
    u64 bgw = wb[w], fgw = ~wb[w];

    // Phase A: all 16 rows' column distances -> LDS, single barrier after.
    int bi0 = i0 & 63;
    u64 lowmask = ((1ull << bi0) << 1) - 1ull;          // bits 0..bi
#pragma unroll
    for (int rl = 0; rl < ROWS_PG; ++rl) {
        int i = i0 + rl;
        u64 himask = ~(lowmask >> 1);                   // bits bi..63
        // bg: set = (t == c)
        u64 lo = bgw & lowmask;
        int last = lo ? (w * 64 + 63 - __builtin_clzll(lo | 1ull)) : Pbg;
        u64 hi = bgw & himask;
        int next = hi ? (w * 64 + (int)__builtin_ctzll(hi | 0x8000000000000000ull)) : Nbg;
        float fwd = (last >= 0) ? (float)(i - last) : (INF_F + (float)(i + 1));
        float bwd = (next >= 0) ? (float)(next - i) : (INF_F + (float)(HH - i));
        float gb = fminf(fwd, bwd);
        // fg: set = (t != c)
        lo = fgw & lowmask;
        last = lo ? (w * 64 + 63 - __builtin_clzll(lo | 1ull)) : Pfg;
        hi = fgw & himask;
        next = hi ? (w * 64 + (int)__builtin_ctzll(hi | 0x8000000000000000ull)) : Nfg;
        fwd = (last >= 0) ? (float)(i - last) : (INF_F + (float)(i + 1));
        bwd = (next >= 0) ? (float)(next - i) : (INF_F + (float)(HH - i));
        float gf = fminf(fwd, bwd);
        g2all[rl][0][j] = gf * gf;
        g2all[rl][1][j] = gb * gb;
        lowmask = (lowmask << 1) | 1ull;
    }
    __syncthreads();

    // Phase B: softmax-weighted accumulation with logits software pipeline.
    const float* lg = logits + ((size_t)b * CC * HH + i0) * WW + j;  // class0,row i0
    float l0 = lg[0], l1 = lg[PLANE], l2 = lg[2 * PLANE];
    float sfg = 0.f, sbg = 0.f, mfg = 0.f, mbg = 0.f;
#pragma unroll 2
    for (int rl = 0; rl < ROWS_PG; ++rl) {
        float n0 = 0.f, n1 = 0.f, n2 = 0.f;
        if (rl < ROWS_PG - 1) {            // prefetch next row's logits
            const float* ln = lg + (size_t)(rl + 1) * WW;
            n0 = ln[0]; n1 = ln[PLANE]; n2 = ln[2 * PLANE];
        }
        float mx = fmaxf(l0, fmaxf(l1, l2));
        float x0 = __expf(l0 - mx), x1 = __expf(l1 - mx), x2 = __expf(l2 - mx);
        float pr = __fdividef((c == 0) ? x0 : (c == 1) ? x1 : x2, x0 + x1 + x2);

        const float* g2 = g2all[rl][0];    // fg
        float mn = g2[j];
        {
            float rr = 1.f, dr = 3.f;      // rr = r*r, exact fp32 integers
            for (int r = 1; r < WW; ++r) {
                if (rr >= mn) break;       // all further candidates >= rr >= mn
                int kl = j - r, kr = j + r;
                if (kl >= 0) mn = fminf(mn, rr + g2[kl]);
                if (kr < WW) mn = fminf(mn, rr + g2[kr]);
                rr += dr; dr += 2.f;
            }
        }
        float df = sqrtf(mn);

        g2 = g2all[rl][1];                 // bg
        mn = g2[j];
        {
            float rr = 1.f, dr = 3.f;
            for (int r = 1; r < WW; ++r) {
                if (rr >= mn) break;
                int kl = j - r, kr = j + r;
                if (kl >= 0) mn = fminf(mn, rr + g2[kl]);
                if (kr < WW) mn = fminf(mn, rr + g2[kr]);
                rr += dr; dr += 2.f;
            }
        }
        float db = sqrtf(mn);

        sfg += pr * df;  sbg += pr * db;
        mfg = fmaxf(mfg, df);  mbg = fmaxf(mbg, db);
        l0 = n0; l1 = n1; l2 = n2;
    }

    // block reduce the 4 accumulators
    int lane = j & 63, wid = j >> 6;
    for (int off = 32; off > 0; off >>= 1) {
        sfg += __shfl_down(sfg, off);
        sbg += __shfl_down(sbg, off);
        mfg = fmaxf(mfg, __shfl_down(mfg, off));
        mbg = fmaxf(mbg, __shfl_down(mbg, off));
    }
    if (lane == 0) { red[0][wid] = sfg; red[1][wid] = sbg; red[2][wid] = mfg; red[3][wid] = mbg; }
    __syncthreads();
    if (j == 0) {
        float a = red[0][0], s = red[1][0], mf = red[2][0], mb = red[3][0];
#pragma unroll
        for (int t = 1; t < WW / 64; ++t) {
            a += red[0][t]; s += red[1][t];
            mf = fmaxf(mf, red[2][t]); mb = fmaxf(mb, red[3][t]);
        }
        float* p = out4f + 4 * ((size_t)(b * CC + c) * GROUPS + g);
        __hip_atomic_store(p + 0, a,  __ATOMIC_RELAXED, __HIP_MEMORY_SCOPE_AGENT);
        __hip_atomic_store(p + 1, s,  __ATOMIC_RELAXED, __HIP_MEMORY_SCOPE_AGENT);
        __hip_atomic_store(p + 2, mf, __ATOMIC_RELAXED, __HIP_MEMORY_SCOPE_AGENT);
        __hip_atomic_store(p + 3, mb, __ATOMIC_RELAXED, __HIP_MEMORY_SCOPE_AGENT);
        __threadfence();   // release: partial visible before ticket
        sticket = __hip_atomic_fetch_add(counter, 1u, __ATOMIC_ACQ_REL,
                                         __HIP_MEMORY_SCOPE_AGENT);
    }
    __syncthreads();
    if (sticket == NBLK - 1) {
        // last arriving block: all 576 partials are globally visible
        __threadfence();   // acquire
        int mask = j >> 4, l = j & 15;          // 24 masks x 16 lanes = 384
        float asf = 0.f, asb = 0.f, amf = 0.f, amb = 0.f;
        for (int gg = l; gg < GROUPS; gg += 16) {
            const float* p = out4f + 4 * ((size_t)mask * GROUPS + gg);
            asf += __hip_atomic_load(p + 0, __ATOMIC_RELAXED, __HIP_MEMORY_SCOPE_AGENT);
            asb += __hip_atomic_load(p + 1, __ATOMIC_RELAXED, __HIP_MEMORY_SCOPE_AGENT);
            amf = fmaxf(amf, __hip_atomic_load(p + 2, __ATOMIC_RELAXED, __HIP_MEMORY_SCOPE_AGENT));
            amb = fmaxf(amb, __hip_atomic_load(p + 3, __ATOMIC_RELAXED, __HIP_MEMORY_SCOPE_AGENT));
        }
#pragma unroll
        for (int off = 8; off > 0; off >>= 1) {
            asf += __shfl_down(asf, off, 16);
            asb += __shfl_down(asb, off, 16);
            amf = fmaxf(amf, __shfl_down(amf, off, 16));
            amb = fmaxf(amb, __shfl_down(amb, off, 16));
        }
        if (l == 0) {
            float cv = 0.f;
            if (amb <= 1000.0f)   // mask non-empty
                cv = asb / fmaxf(amb, 1e-12f) - asf / fmaxf(amf, 1e-12f);
            contrib[mask] = cv;
        }
        __syncthreads();
        if (j == 0) {
            float tot = 0.f;
            for (int mk = 0; mk < NMASK; ++mk) tot += contrib[mk];
            out[0] = tot / (float)((size_t)BB * CC * PLANE);
        }
    }
}

extern "C" void kernel_launch(void* const* d_in, const int* in_sizes, int n_in,
                              void* d_out, int out_size, void* d_ws, size_t ws_size,
                              hipStream_t stream) {
    const float* logits = (const float*)d_in[0];   // [8,3,384,384] f32
    const int* targets = (const int*)d_in[1];      // [8,384,384] i32
    float* out = (float*)d_out;                    // scalar f32

    u64* bm = (u64*)d_ws;                                       // 55296 u64
    float* out4f = (float*)(bm + (size_t)BB * CC * NW * WW);    // 2304 floats
    unsigned* counter = (unsigned*)(out4f + 4 * (size_t)NMASK * GROUPS);

    {
        dim3 grid(BB, NW, 4);                                   // 192 blocks
        buildbm<<<grid, WW, 0, stream>>>(targets, (u16*)bm, counter);
    }
    {
        dim3 grid(GROUPS, BB, CC);                              // 576 blocks
        edt16f<<<grid, WW, 0, stream>>>(bm, logits, out4f, counter, out);
    }
}

// Round 7
// 88.689 us; speedup vs baseline: 1.2617x; 1.2617x over previous
//
#include <hip/hip_runtime.h>

typedef unsigned long long u64;
typedef unsigned short u16;

#define HH 384
#define WW 384
#define BB 8
#define CC 3
#define NMASK (BB*CC)        // 24
#define PLANE (HH*WW)        // 147456
#define NW 6                 // 384 rows = 6 x 64-bit words
#define ROWS_PG 8            // 8 | 64 -> a row group never spans bitmask words
#define GROUPS 48            // 384/8
#define INF_F 1.0e6f

// ---------------------------------------------------------------------------
// Key algebra: only the 3 per-class bg EDT fields d_c(q)=dist(q,{t==c}) are
// computed. fg_c(q)=dist(q,{t!=c}) = 0 where t(q)!=c, else min of the other
// two d's (dist to a union = min of dists — bit-exact: union of identical
// fp32 candidate values; min(sqrt a, sqrt b)=sqrt(min(a,b)) as sqrt is
// monotone & correctly rounded).
// loss = sum_m S_bg/max_bg - S_fg/max_fg  (divide-after-sum; ~1e-7 rel)
// mask non-empty <=> max_bg <= 1000 (real EDT max < 542; empty-set >= 1e6)
//
// ws layout:
//   u64   bm[BB][CC][NW][WW]        column seed bitmasks (442368 B)
//   float out12[NMASK][4][GROUPS]   per-(b,c): {Sbg,Sfg,Mbg,Mfg} x rowgroup
// ---------------------------------------------------------------------------

// Grid (BB, NW, 4): thread j builds a 16-bit partial of the 64-row bitmask
// word for its column, all 3 classes (u16 stores, little-endian, no atomics).
__global__ __launch_bounds__(WW) void buildbm(const int* __restrict__ targets,
                                              u16* __restrict__ bm16) {
    int b = blockIdx.x, w = blockIdx.y, q = blockIdx.z;
    int j = threadIdx.x;
    const int* tg = targets + (size_t)b * PLANE + (w * 64 + q * 16) * WW + j;
    unsigned m0 = 0, m1 = 0, m2 = 0;
#pragma unroll
    for (int r = 0; r < 16; ++r) {
        int t = tg[r * WW];
        unsigned bit = 1u << r;
        m0 |= (t == 0) ? bit : 0u;
        m1 |= (t == 1) ? bit : 0u;
        m2 |= (t == 2) ? bit : 0u;
    }
    size_t base = (((size_t)b * CC) * NW + w) * WW + j;          // c = 0
    bm16[base * 4 + q] = (u16)m0;
    bm16[(base + (size_t)NW * WW) * 4 + q] = (u16)m1;
    bm16[(base + 2 * (size_t)NW * WW) * 4 + q] = (u16)m2;
}

// Grid (GROUPS, BB): block = 8 rows x 384 cols, ALL 3 classes.
// Phase A: thread j loads 6 bitmask words per class, computes cross-word
// prev/next anchors, emits 8 rows x 3 classes of exact column distances
// (bit-identical to the reference scan) squared into LDS. One barrier.
// Phase B: per row: softmax once, 3 ring searches (safe prune rr>=mn),
// fg derived from label bit + cross-class min, register accumulation.
__global__ __launch_bounds__(WW) void edt8(const u64* __restrict__ bm,
                                           const float* __restrict__ logits,
                                           float* __restrict__ out12) {
    __shared__ float g2s[ROWS_PG][CC][WW];    // 36864 B
    __shared__ float red[12][WW / 64];
    int g = blockIdx.x, b = blockIdx.y;
    int j = threadIdx.x;
    int i0 = g * ROWS_PG;
    int w = i0 >> 6;
    int wbase = w << 6;

    u64 word[CC];
    int P[CC], N[CC];
#pragma unroll
    for (int c = 0; c < CC; ++c) {
        u64 wb[NW];
#pragma unroll
        for (int wq = 0; wq < NW; ++wq)
            wb[wq] = bm[(((size_t)b * CC + c) * NW + wq) * WW + j];
        int p = -1, n = -1;
#pragma unroll
        for (int wq = 0; wq < NW; ++wq)
            if (wq < w && wb[wq]) p = wq * 64 + 63 - __builtin_clzll(wb[wq] | 1ull);
#pragma unroll
        for (int wq = NW - 1; wq >= 0; --wq)
            if (wq > w && wb[wq]) n = wq * 64 + (int)__builtin_ctzll(wb[wq] | 0x8000000000000000ull);
        P[c] = p; N[c] = n;
        word[c] = wb[w];
    }

    // Phase A: 8 rows x 3 classes of exact column distances -> LDS.
    u64 lowmask = ((1ull << (i0 & 63)) << 1) - 1ull;    // bits 0..bi
#pragma unroll
    for (int rl = 0; rl < ROWS_PG; ++rl) {
        int i = i0 + rl;
        u64 himask = ~(lowmask >> 1);                   // bits bi..63
#pragma unroll
        for (int c = 0; c < CC; ++c) {
            u64 lo = word[c] & lowmask;
            int last = lo ? (wbase + 63 - __builtin_clzll(lo | 1ull)) : P[c];
            u64 hi = word[c] & himask;
            int next = hi ? (wbase + (int)__builtin_ctzll(hi | 0x8000000000000000ull)) : N[c];
            float fwd = (last >= 0) ? (float)(i - last) : (INF_F + (float)(i + 1));
            float bwd = (next >= 0) ? (float)(next - i) : (INF_F + (float)(HH - i));
            float gc = fminf(fwd, bwd);
            g2s[rl][c][j] = gc * gc;
        }
        lowmask = (lowmask << 1) | 1ull;
    }
    __syncthreads();

    // Phase B
    float Sb0 = 0.f, Sb1 = 0.f, Sb2 = 0.f, Sf0 = 0.f, Sf1 = 0.f, Sf2 = 0.f;
    float Mb0 = 0.f, Mb1 = 0.f, Mb2 = 0.f, Mf0 = 0.f, Mf1 = 0.f, Mf2 = 0.f;
    const float* lg = logits + ((size_t)b * CC * HH + i0) * WW + j;
#pragma unroll
    for (int rl = 0; rl < ROWS_PG; ++rl) {
        int bi = (i0 + rl) & 63;
        float l0 = lg[rl * WW], l1 = lg[PLANE + rl * WW], l2 = lg[2 * PLANE + rl * WW];
        float mx = fmaxf(l0, fmaxf(l1, l2));
        float x0 = __expf(l0 - mx), x1 = __expf(l1 - mx), x2 = __expf(l2 - mx);
        float rs = __fdividef(1.0f, x0 + x1 + x2);
        float pr0 = x0 * rs, pr1 = x1 * rs, pr2 = x2 * rs;

        float d[CC];
#pragma unroll
        for (int c = 0; c < CC; ++c) {
            const float* g2 = g2s[rl][c];
            float mn = g2[j];
            float rr = 1.f, dr = 3.f;       // rr = r*r, exact fp32 integers
            for (int r = 1; r < WW; ++r) {
                if (rr >= mn) break;        // candidates at >= r are >= rr >= mn
                int kl = j - r, kr = j + r;
                if (kl >= 0) mn = fminf(mn, rr + g2[kl]);
                if (kr < WW) mn = fminf(mn, rr + g2[kr]);
                rr += dr; dr += 2.f;
            }
            d[c] = sqrtf(mn);
        }
        // fg_c = (t==c) ? min of other two d's : 0
        float f0 = ((word[0] >> bi) & 1ull) ? fminf(d[1], d[2]) : 0.f;
        float f1 = ((word[1] >> bi) & 1ull) ? fminf(d[0], d[2]) : 0.f;
        float f2 = ((word[2] >> bi) & 1ull) ? fminf(d[0], d[1]) : 0.f;

        Sb0 += pr0 * d[0]; Sb1 += pr1 * d[1]; Sb2 += pr2 * d[2];
        Sf0 += pr0 * f0;   Sf1 += pr1 * f1;   Sf2 += pr2 * f2;
        Mb0 = fmaxf(Mb0, d[0]); Mb1 = fmaxf(Mb1, d[1]); Mb2 = fmaxf(Mb2, d[2]);
        Mf0 = fmaxf(Mf0, f0);   Mf1 = fmaxf(Mf1, f1);   Mf2 = fmaxf(Mf2, f2);
    }

    // block-reduce the 12 accumulators
    float acc[12] = {Sb0, Sf0, Mb0, Mf0, Sb1, Sf1, Mb1, Mf1, Sb2, Sf2, Mb2, Mf2};
    int lane = j & 63, wid = j >> 6;
#pragma unroll
    for (int a = 0; a < 12; ++a) {
        bool ismax = (a & 2) != 0;         // k = a&3: 0,1 sums; 2,3 maxes
        float v = acc[a];
        for (int off = 32; off > 0; off >>= 1) {
            float o = __shfl_down(v, off);
            v = ismax ? fmaxf(v, o) : (v + o);
        }
        if (lane == 0) red[a][wid] = v;
    }
    __syncthreads();
    if (j < 12) {
        int c = j >> 2, k = j & 3;
        bool ismax = (k & 2) != 0;
        float v = red[j][0];
#pragma unroll
        for (int t = 1; t < WW / 64; ++t)
            v = ismax ? fmaxf(v, red[j][t]) : (v + red[j][t]);
        out12[((size_t)(b * CC + c) * 4 + k) * GROUPS + g] = v;
    }
}

// One block: reduce 24 masks x 4 stats x 48 groups -> scalar loss.
__global__ __launch_bounds__(WW) void final_k(const float* __restrict__ out12,
                                              float* __restrict__ out) {
    __shared__ float contrib[NMASK];
    int t = threadIdx.x;
    int m = t >> 4, l = t & 15;            // 24 masks x 16 lanes
    float sb = 0.f, sf = 0.f, mb = 0.f, mf = 0.f;
    for (int gg = l; gg < GROUPS; gg += 16) {
        const float* p = out12 + (size_t)m * 4 * GROUPS + gg;
        sb += p[0 * GROUPS];
        sf += p[1 * GROUPS];
        mb = fmaxf(mb, p[2 * GROUPS]);
        mf = fmaxf(mf, p[3 * GROUPS]);
    }
#pragma unroll
    for (int off = 8; off > 0; off >>= 1) {
        sb += __shfl_down(sb, off, 16);
        sf += __shfl_down(sf, off, 16);
        mb = fmaxf(mb, __shfl_down(mb, off, 16));
        mf = fmaxf(mf, __shfl_down(mf, off, 16));
    }
    if (l == 0) {
        float cv = 0.f;
        if (mb <= 1000.0f)                 // mask non-empty
            cv = sb / fmaxf(mb, 1e-12f) - sf / fmaxf(mf, 1e-12f);
        contrib[m] = cv;
    }
    __syncthreads();
    if (t == 0) {
        float tot = 0.f;
        for (int mk = 0; mk < NMASK; ++mk) tot += contrib[mk];
        out[0] = tot / (float)((size_t)BB * CC * PLANE);
    }
}

extern "C" void kernel_launch(void* const* d_in, const int* in_sizes, int n_in,
                              void* d_out, int out_size, void* d_ws, size_t ws_size,
                              hipStream_t stream) {
    const float* logits = (const float*)d_in[0];   // [8,3,384,384] f32
    const int* targets = (const int*)d_in[1];      // [8,384,384] i32
    float* out = (float*)d_out;                    // scalar f32

    u64* bm = (u64*)d_ws;                                       // 55296 u64
    float* out12 = (float*)(bm + (size_t)BB * CC * NW * WW);    // 4608 floats

    {
        dim3 grid(BB, NW, 4);                                   // 192 blocks
        buildbm<<<grid, WW, 0, stream>>>(targets, (u16*)bm);
    }
    {
        dim3 grid(GROUPS, BB);                                  // 48*8 = 384 blocks
        edt8<<<grid, WW, 0, stream>>>(bm, logits, out12);
    }
    final_k<<<1, WW, 0, stream>>>(out12, out);
}

// Round 8
// 86.398 us; speedup vs baseline: 1.2952x; 1.0265x over previous
//
#include <hip/hip_runtime.h>

typedef unsigned long long u64;
typedef unsigned short u16;

#define HH 384
#define WW 384
#define BB 8
#define CC 3
#define NMASK (BB*CC)        // 24
#define PLANE (HH*WW)        // 147456
#define NW 6                 // 384 rows = 6 x 64-bit words
#define ROWS_PG 4            // 4 | 64 -> a row group never spans bitmask words
#define GROUPS 96            // 384/4 -> 768 blocks = 3/CU
#define CHUNK 4              // ring radii per pipelined LDS batch
#define INF_F 1.0e6f

// ---------------------------------------------------------------------------
// Algebra: only the 3 per-class bg EDT fields d_c(q)=dist(q,{t==c}) are
// computed. fg_c(q)=dist(q,{t!=c}) = 0 where t(q)!=c, else min of the other
// two d's (dist-to-union = min of dists; bit-exact, sqrt monotone).
// loss = sum_m S_bg/max_bg - S_fg/max_fg  (divide-after-sum; ~1e-7 rel)
// mask non-empty <=> max_bg <= 1000 (real EDT max < 542; empty-set >= 1e6)
// Ring search exactness: candidates are fl(r^2 + g2[k]) — identical to the
// reference's fl(offs + g^2). OOB clamp to k=0 / k=WW-1 adds only candidates
// fl(r^2+g2[edge]) >= fl(dist_true^2+g2[edge]) (fp32 add monotone) — a value
// >= an existing true candidate, so the min is unchanged. Chunk overshoot
// (evaluating radii past the break point) adds only such safe candidates too.
//
// ws layout:
//   u64   bm[BB][CC][NW][WW]        column seed bitmasks (442368 B)
//   float out12[NMASK][4][GROUPS]   per-(b,c): {Sbg,Sfg,Mbg,Mfg} x rowgroup
// ---------------------------------------------------------------------------

// Grid (BB, NW, 4): thread j builds a 16-bit partial of the 64-row bitmask
// word for its column, all 3 classes (u16 stores, little-endian, no atomics).
__global__ __launch_bounds__(WW) void buildbm(const int* __restrict__ targets,
                                              u16* __restrict__ bm16) {
    int b = blockIdx.x, w = blockIdx.y, q = blockIdx.z;
    int j = threadIdx.x;
    const int* tg = targets + (size_t)b * PLANE + (w * 64 + q * 16) * WW + j;
    unsigned m0 = 0, m1 = 0, m2 = 0;
#pragma unroll
    for (int r = 0; r < 16; ++r) {
        int t = tg[r * WW];
        unsigned bit = 1u << r;
        m0 |= (t == 0) ? bit : 0u;
        m1 |= (t == 1) ? bit : 0u;
        m2 |= (t == 2) ? bit : 0u;
    }
    size_t base = (((size_t)b * CC) * NW + w) * WW + j;          // c = 0
    bm16[base * 4 + q] = (u16)m0;
    bm16[(base + (size_t)NW * WW) * 4 + q] = (u16)m1;
    bm16[(base + 2 * (size_t)NW * WW) * 4 + q] = (u16)m2;
}

// Grid (GROUPS, BB): block = 4 rows x 384 cols, all 3 classes.
__global__ __launch_bounds__(WW) void edt4(const u64* __restrict__ bm,
                                           const float* __restrict__ logits,
                                           float* __restrict__ out12) {
    __shared__ float g2s[ROWS_PG][CC][WW];    // 18432 B
    __shared__ float red[12][WW / 64];
    int g = blockIdx.x, b = blockIdx.y;
    int j = threadIdx.x;
    int i0 = g * ROWS_PG;
    int w = i0 >> 6;
    int wbase = w << 6;

    u64 word[CC];
    int P[CC], N[CC];
#pragma unroll
    for (int c = 0; c < CC; ++c) {
        u64 wb[NW];
#pragma unroll
        for (int wq = 0; wq < NW; ++wq)
            wb[wq] = bm[(((size_t)b * CC + c) * NW + wq) * WW + j];
        int p = -1, n = -1;
#pragma unroll
        for (int wq = 0; wq < NW; ++wq)
            if (wq < w && wb[wq]) p = wq * 64 + 63 - __builtin_clzll(wb[wq] | 1ull);
#pragma unroll
        for (int wq = NW - 1; wq >= 0; --wq)
            if (wq > w && wb[wq]) n = wq * 64 + (int)__builtin_ctzll(wb[wq] | 0x8000000000000000ull);
        P[c] = p; N[c] = n;
        word[c] = wb[w];
    }

    // Phase A: 4 rows x 3 classes of exact column distances -> LDS.
    u64 lowmask = ((1ull << (i0 & 63)) << 1) - 1ull;    // bits 0..bi
#pragma unroll
    for (int rl = 0; rl < ROWS_PG; ++rl) {
        int i = i0 + rl;
        u64 himask = ~(lowmask >> 1);                   // bits bi..63
#pragma unroll
        for (int c = 0; c < CC; ++c) {
            u64 lo = word[c] & lowmask;
            int last = lo ? (wbase + 63 - __builtin_clzll(lo | 1ull)) : P[c];
            u64 hi = word[c] & himask;
            int next = hi ? (wbase + (int)__builtin_ctzll(hi | 0x8000000000000000ull)) : N[c];
            float fwd = (last >= 0) ? (float)(i - last) : (INF_F + (float)(i + 1));
            float bwd = (next >= 0) ? (float)(next - i) : (INF_F + (float)(HH - i));
            float gc = fminf(fwd, bwd);
            g2s[rl][c][j] = gc * gc;
        }
        lowmask = (lowmask << 1) | 1ull;
    }
    __syncthreads();

    // Phase B: per row, softmax once + 3 chunked ring searches.
    float Sb0 = 0.f, Sb1 = 0.f, Sb2 = 0.f, Sf0 = 0.f, Sf1 = 0.f, Sf2 = 0.f;
    float Mb0 = 0.f, Mb1 = 0.f, Mb2 = 0.f, Mf0 = 0.f, Mf1 = 0.f, Mf2 = 0.f;
    const float* lg = logits + ((size_t)b * CC * HH + i0) * WW + j;
#pragma unroll
    for (int rl = 0; rl < ROWS_PG; ++rl) {
        int bi = (i0 + rl) & 63;
        float l0 = lg[rl * WW], l1 = lg[PLANE + rl * WW], l2 = lg[2 * PLANE + rl * WW];
        float mx = fmaxf(l0, fmaxf(l1, l2));
        float x0 = __expf(l0 - mx), x1 = __expf(l1 - mx), x2 = __expf(l2 - mx);
        float rs = __fdividef(1.0f, x0 + x1 + x2);
        float pr0 = x0 * rs, pr1 = x1 * rs, pr2 = x2 * rs;

        float d[CC];
#pragma unroll
        for (int c = 0; c < CC; ++c) {
            const float* g2 = g2s[rl][c];
            float mn = g2[j];
            for (int r0 = 1; r0 < WW; r0 += CHUNK) {
                float r0sq = (float)(r0 * r0);       // exact fp32 integer
                if (r0sq >= mn) break;               // all r >= r0 candidates >= mn
                // 2*CHUNK independent clamped LDS loads, then a min tree
                float cl[CHUNK], cr[CHUNK];
#pragma unroll
                for (int u = 0; u < CHUNK; ++u) {
                    int r = r0 + u;
                    int kl = j - r; kl = (kl < 0) ? 0 : kl;
                    int kr = j + r; kr = (kr > WW - 1) ? WW - 1 : kr;
                    cl[u] = g2[kl];
                    cr[u] = g2[kr];
                }
                float cand = 3.4e38f;
#pragma unroll
                for (int u = 0; u < CHUNK; ++u) {
                    float rr = (float)((r0 + u) * (r0 + u));   // exact
                    cand = fminf(cand, fminf(rr + cl[u], rr + cr[u]));
                }
                mn = fminf(mn, cand);
            }
            d[c] = sqrtf(mn);
        }
        // fg_c = (t==c) ? min of other two bg dists : 0
        float f0 = ((word[0] >> bi) & 1ull) ? fminf(d[1], d[2]) : 0.f;
        float f1 = ((word[1] >> bi) & 1ull) ? fminf(d[0], d[2]) : 0.f;
        float f2 = ((word[2] >> bi) & 1ull) ? fminf(d[0], d[1]) : 0.f;

        Sb0 += pr0 * d[0]; Sb1 += pr1 * d[1]; Sb2 += pr2 * d[2];
        Sf0 += pr0 * f0;   Sf1 += pr1 * f1;   Sf2 += pr2 * f2;
        Mb0 = fmaxf(Mb0, d[0]); Mb1 = fmaxf(Mb1, d[1]); Mb2 = fmaxf(Mb2, d[2]);
        Mf0 = fmaxf(Mf0, f0);   Mf1 = fmaxf(Mf1, f1);   Mf2 = fmaxf(Mf2, f2);
    }

    // block-reduce the 12 accumulators
    float acc[12] = {Sb0, Sf0, Mb0, Mf0, Sb1, Sf1, Mb1, Mf1, Sb2, Sf2, Mb2, Mf2};
    int lane = j & 63, wid = j >> 6;
#pragma unroll
    for (int a = 0; a < 12; ++a) {
        bool ismax = (a & 2) != 0;         // k = a&3: 0,1 sums; 2,3 maxes
        float v = acc[a];
        for (int off = 32; off > 0; off >>= 1) {
            float o = __shfl_down(v, off);
            v = ismax ? fmaxf(v, o) : (v + o);
        }
        if (lane == 0) red[a][wid] = v;
    }
    __syncthreads();
    if (j < 12) {
        int c = j >> 2, k = j & 3;
        bool ismax = (k & 2) != 0;
        float v = red[j][0];
#pragma unroll
        for (int t = 1; t < WW / 64; ++t)
            v = ismax ? fmaxf(v, red[j][t]) : (v + red[j][t]);
        out12[((size_t)(b * CC + c) * 4 + k) * GROUPS + g] = v;
    }
}

// One block: reduce 24 masks x 4 stats x 96 groups -> scalar loss.
__global__ __launch_bounds__(WW) void final_k(const float* __restrict__ out12,
                                              float* __restrict__ out) {
    __shared__ float contrib[NMASK];
    int t = threadIdx.x;
    int m = t >> 4, l = t & 15;            // 24 masks x 16 lanes
    float sb = 0.f, sf = 0.f, mb = 0.f, mf = 0.f;
    for (int gg = l; gg < GROUPS; gg += 16) {
        const float* p = out12 + (size_t)m * 4 * GROUPS + gg;
        sb += p[0 * GROUPS];
        sf += p[1 * GROUPS];
        mb = fmaxf(mb, p[2 * GROUPS]);
        mf = fmaxf(mf, p[3 * GROUPS]);
    }
#pragma unroll
    for (int off = 8; off > 0; off >>= 1) {
        sb += __shfl_down(sb, off, 16);
        sf += __shfl_down(sf, off, 16);
        mb = fmaxf(mb, __shfl_down(mb, off, 16));
        mf = fmaxf(mf, __shfl_down(mf, off, 16));
    }
    if (l == 0) {
        float cv = 0.f;
        if (mb <= 1000.0f)                 // mask non-empty
            cv = sb / fmaxf(mb, 1e-12f) - sf / fmaxf(mf, 1e-12f);
        contrib[m] = cv;
    }
    __syncthreads();
    if (t == 0) {
        float tot = 0.f;
        for (int mk = 0; mk < NMASK; ++mk) tot += contrib[mk];
        out[0] = tot / (float)((size_t)BB * CC * PLANE);
    }
}

extern "C" void kernel_launch(void* const* d_in, const int* in_sizes, int n_in,
                              void* d_out, int out_size, void* d_ws, size_t ws_size,
                              hipStream_t stream) {
    const float* logits = (const float*)d_in[0];   // [8,3,384,384] f32
    const int* targets = (const int*)d_in[1];      // [8,384,384] i32
    float* out = (float*)d_out;                    // scalar f32

    u64* bm = (u64*)d_ws;                                       // 55296 u64
    float* out12 = (float*)(bm + (size_t)BB * CC * NW * WW);    // 9216 floats

    {
        dim3 grid(BB, NW, 4);                                   // 192 blocks
        buildbm<<<grid, WW, 0, stream>>>(targets, (u16*)bm);
    }
    {
        dim3 grid(GROUPS, BB);                                  // 96*8 = 768 blocks
        edt4<<<grid, WW, 0, stream>>>(bm, logits, out12);
    }
    final_k<<<1, WW, 0, stream>>>(out12, out);
}

// Round 9
// 85.650 us; speedup vs baseline: 1.3065x; 1.0087x over previous
//
#include <hip/hip_runtime.h>

typedef unsigned long long u64;
typedef unsigned short u16;

#define HH 384
#define WW 384
#define BB 8
#define CC 3
#define NMASK (BB*CC)        // 24
#define PLANE (HH*WW)        // 147456
#define NW 6                 // 384 rows = 6 x 64-bit words
#define ROWS_PG 2            // 2 | 64 -> a row group never spans bitmask words
#define GROUPS 192           // 384/2 -> 1536 blocks ≈ 6/CU
#define CHUNK 4              // fallback ring radii per batch
#define INF_F 1.0e6f

// ---------------------------------------------------------------------------
// Algebra: only the 3 per-class bg EDT fields d_c(q)=dist(q,{t==c}) are
// computed. fg_c(q)=dist(q,{t!=c}) = 0 where t(q)!=c, else min of the other
// two d's (dist-to-union = min of dists; bit-exact, sqrt monotone).
// loss = sum_m S_bg/max_bg - S_fg/max_fg  (divide-after-sum; ~1e-7 rel)
// mask non-empty <=> max_bg <= 1000 (real EDT max < 542; empty-set >= 1e6)
//
// Row-EDT: fixed aligned window [base, base+20) ⊇ [j-8, j+8] of candidates
// fl((k-j)^2 + g2[k]) — each is an exact reference candidate (diff^2 is an
// exact fp32 integer, fmaf rounds = fl(fl(diff^2)+g2)). If mn <= 81 all
// radius>=9 candidates are >= 81 >= mn (fp32 add of nonnegatives monotone)
// -> done; else rare serial fallback from r=9 (clamped indices add only
// candidates >= an existing true candidate — safe).
//
// ws layout:
//   u64   bm[BB][CC][NW][WW]        column seed bitmasks (442368 B)
//   float out12[NMASK][4][GROUPS]   per-(b,c): {Sbg,Sfg,Mbg,Mfg} x rowgroup
// ---------------------------------------------------------------------------

// Grid (BB, NW, 4): thread j builds a 16-bit partial of the 64-row bitmask
// word for its column, all 3 classes (u16 stores, little-endian, no atomics).
__global__ __launch_bounds__(WW) void buildbm(const int* __restrict__ targets,
                                              u16* __restrict__ bm16) {
    int b = blockIdx.x, w = blockIdx.y, q = blockIdx.z;
    int j = threadIdx.x;
    const int* tg = targets + (size_t)b * PLANE + (w * 64 + q * 16) * WW + j;
    unsigned m0 = 0, m1 = 0, m2 = 0;
#pragma unroll
    for (int r = 0; r < 16; ++r) {
        int t = tg[r * WW];
        unsigned bit = 1u << r;
        m0 |= (t == 0) ? bit : 0u;
        m1 |= (t == 1) ? bit : 0u;
        m2 |= (t == 2) ? bit : 0u;
    }
    size_t base = (((size_t)b * CC) * NW + w) * WW + j;          // c = 0
    bm16[base * 4 + q] = (u16)m0;
    bm16[(base + (size_t)NW * WW) * 4 + q] = (u16)m1;
    bm16[(base + 2 * (size_t)NW * WW) * 4 + q] = (u16)m2;
}

// Grid (GROUPS, BB): block = 2 rows x 384 cols, all 3 classes.
__global__ __launch_bounds__(WW) void edt2(const u64* __restrict__ bm,
                                           const float* __restrict__ logits,
                                           float* __restrict__ out12) {
    __shared__ __align__(16) float g2s[ROWS_PG][CC][WW];   // 9216 B
    __shared__ float red[12][WW / 64];
    int g = blockIdx.x, b = blockIdx.y;
    int j = threadIdx.x;
    int i0 = g * ROWS_PG;
    int w = i0 >> 6;
    int wbase = w << 6;

    u64 word[CC];
    int P[CC], N[CC];
#pragma unroll
    for (int c = 0; c < CC; ++c) {
        u64 wb[NW];
#pragma unroll
        for (int wq = 0; wq < NW; ++wq)
            wb[wq] = bm[(((size_t)b * CC + c) * NW + wq) * WW + j];
        int p = -1, n = -1;
#pragma unroll
        for (int wq = 0; wq < NW; ++wq)
            if (wq < w && wb[wq]) p = wq * 64 + 63 - __builtin_clzll(wb[wq] | 1ull);
#pragma unroll
        for (int wq = NW - 1; wq >= 0; --wq)
            if (wq > w && wb[wq]) n = wq * 64 + (int)__builtin_ctzll(wb[wq] | 0x8000000000000000ull);
        P[c] = p; N[c] = n;
        word[c] = wb[w];
    }

    // Phase A: 2 rows x 3 classes of exact column distances -> LDS.
    u64 lowmask = ((1ull << (i0 & 63)) << 1) - 1ull;    // bits 0..bi
#pragma unroll
    for (int rl = 0; rl < ROWS_PG; ++rl) {
        int i = i0 + rl;
        u64 himask = ~(lowmask >> 1);                   // bits bi..63
#pragma unroll
        for (int c = 0; c < CC; ++c) {
            u64 lo = word[c] & lowmask;
            int last = lo ? (wbase + 63 - __builtin_clzll(lo | 1ull)) : P[c];
            u64 hi = word[c] & himask;
            int next = hi ? (wbase + (int)__builtin_ctzll(hi | 0x8000000000000000ull)) : N[c];
            float fwd = (last >= 0) ? (float)(i - last) : (INF_F + (float)(i + 1));
            float bwd = (next >= 0) ? (float)(next - i) : (INF_F + (float)(HH - i));
            float gc = fminf(fwd, bwd);
            g2s[rl][c][j] = gc * gc;
        }
        lowmask = (lowmask << 1) | 1ull;
    }
    __syncthreads();

    // aligned window base covering [j-8, j+8]
    int basek = (j - 8) & ~3;
    if (basek < 0) basek = 0;
    if (basek > WW - 20) basek = WW - 20;
    float df0 = (float)(basek - j);

    // Phase B: per row, softmax once + 3 window searches (+rare fallback).
    float Sb0 = 0.f, Sb1 = 0.f, Sb2 = 0.f, Sf0 = 0.f, Sf1 = 0.f, Sf2 = 0.f;
    float Mb0 = 0.f, Mb1 = 0.f, Mb2 = 0.f, Mf0 = 0.f, Mf1 = 0.f, Mf2 = 0.f;
    const float* lg = logits + ((size_t)b * CC * HH + i0) * WW + j;
#pragma unroll
    for (int rl = 0; rl < ROWS_PG; ++rl) {
        int bi = (i0 + rl) & 63;
        float l0 = lg[rl * WW], l1 = lg[PLANE + rl * WW], l2 = lg[2 * PLANE + rl * WW];
        float mx = fmaxf(l0, fmaxf(l1, l2));
        float x0 = __expf(l0 - mx), x1 = __expf(l1 - mx), x2 = __expf(l2 - mx);
        float rs = __fdividef(1.0f, x0 + x1 + x2);
        float pr0 = x0 * rs, pr1 = x1 * rs, pr2 = x2 * rs;

        float d[CC];
#pragma unroll
        for (int c = 0; c < CC; ++c) {
            const float* g2 = g2s[rl][c];
            // 5 independent b128 loads — one latency wait, no chain
            float4 W0 = *(const float4*)(g2 + basek);
            float4 W1 = *(const float4*)(g2 + basek + 4);
            float4 W2 = *(const float4*)(g2 + basek + 8);
            float4 W3 = *(const float4*)(g2 + basek + 12);
            float4 W4 = *(const float4*)(g2 + basek + 16);
            float df = df0;
            float mn = 3.4e38f;
            const float4 Ws[5] = {W0, W1, W2, W3, W4};
#pragma unroll
            for (int q = 0; q < 5; ++q) {
                mn = fminf(mn, fmaf(df, df, Ws[q].x)); df += 1.f;
                mn = fminf(mn, fmaf(df, df, Ws[q].y)); df += 1.f;
                mn = fminf(mn, fmaf(df, df, Ws[q].z)); df += 1.f;
                mn = fminf(mn, fmaf(df, df, Ws[q].w)); df += 1.f;
            }
            if (mn > 81.f) {               // rare: radius-9 prune failed
                for (int r0 = 9; r0 < WW; r0 += CHUNK) {
                    float r0sq = (float)(r0 * r0);   // exact fp32 integer
                    if (r0sq >= mn) break;
                    float cl[CHUNK], cr[CHUNK];
#pragma unroll
                    for (int u = 0; u < CHUNK; ++u) {
                        int r = r0 + u;
                        int kl = j - r; kl = (kl < 0) ? 0 : kl;
                        int kr = j + r; kr = (kr > WW - 1) ? WW - 1 : kr;
                        cl[u] = g2[kl];
                        cr[u] = g2[kr];
                    }
#pragma unroll
                    for (int u = 0; u < CHUNK; ++u) {
                        float rr = (float)((r0 + u) * (r0 + u));
                        mn = fminf(mn, fminf(rr + cl[u], rr + cr[u]));
                    }
                }
            }
            d[c] = sqrtf(mn);
        }
        // fg_c = (t==c) ? min of other two bg dists : 0
        float f0 = ((word[0] >> bi) & 1ull) ? fminf(d[1], d[2]) : 0.f;
        float f1 = ((word[1] >> bi) & 1ull) ? fminf(d[0], d[2]) : 0.f;
        float f2 = ((word[2] >> bi) & 1ull) ? fminf(d[0], d[1]) : 0.f;

        Sb0 += pr0 * d[0]; Sb1 += pr1 * d[1]; Sb2 += pr2 * d[2];
        Sf0 += pr0 * f0;   Sf1 += pr1 * f1;   Sf2 += pr2 * f2;
        Mb0 = fmaxf(Mb0, d[0]); Mb1 = fmaxf(Mb1, d[1]); Mb2 = fmaxf(Mb2, d[2]);
        Mf0 = fmaxf(Mf0, f0);   Mf1 = fmaxf(Mf1, f1);   Mf2 = fmaxf(Mf2, f2);
    }

    // block-reduce the 12 accumulators
    float acc[12] = {Sb0, Sf0, Mb0, Mf0, Sb1, Sf1, Mb1, Mf1, Sb2, Sf2, Mb2, Mf2};
    int lane = j & 63, wid = j >> 6;
#pragma unroll
    for (int a = 0; a < 12; ++a) {
        bool ismax = (a & 2) != 0;         // k = a&3: 0,1 sums; 2,3 maxes
        float v = acc[a];
        for (int off = 32; off > 0; off >>= 1) {
            float o = __shfl_down(v, off);
            v = ismax ? fmaxf(v, o) : (v + o);
        }
        if (lane == 0) red[a][wid] = v;
    }
    __syncthreads();
    if (j < 12) {
        int c = j >> 2, k = j & 3;
        bool ismax = (k & 2) != 0;
        float v = red[j][0];
#pragma unroll
        for (int t = 1; t < WW / 64; ++t)
            v = ismax ? fmaxf(v, red[j][t]) : (v + red[j][t]);
        out12[((size_t)(b * CC + c) * 4 + k) * GROUPS + g] = v;
    }
}

// One block: reduce 24 masks x 4 stats x 192 groups -> scalar loss.
__global__ __launch_bounds__(WW) void final_k(const float* __restrict__ out12,
                                              float* __restrict__ out) {
    __shared__ float contrib[NMASK];
    int t = threadIdx.x;
    int m = t >> 4, l = t & 15;            // 24 masks x 16 lanes
    float sb = 0.f, sf = 0.f, mb = 0.f, mf = 0.f;
    for (int gg = l; gg < GROUPS; gg += 16) {
        const float* p = out12 + (size_t)m * 4 * GROUPS + gg;
        sb += p[0 * GROUPS];
        sf += p[1 * GROUPS];
        mb = fmaxf(mb, p[2 * GROUPS]);
        mf = fmaxf(mf, p[3 * GROUPS]);
    }
#pragma unroll
    for (int off = 8; off > 0; off >>= 1) {
        sb += __shfl_down(sb, off, 16);
        sf += __shfl_down(sf, off, 16);
        mb = fmaxf(mb, __shfl_down(mb, off, 16));
        mf = fmaxf(mf, __shfl_down(mf, off, 16));
    }
    if (l == 0) {
        float cv = 0.f;
        if (mb <= 1000.0f)                 // mask non-empty
            cv = sb / fmaxf(mb, 1e-12f) - sf / fmaxf(mf, 1e-12f);
        contrib[m] = cv;
    }
    __syncthreads();
    if (t == 0) {
        float tot = 0.f;
        for (int mk = 0; mk < NMASK; ++mk) tot += contrib[mk];
        out[0] = tot / (float)((size_t)BB * CC * PLANE);
    }
}

extern "C" void kernel_launch(void* const* d_in, const int* in_sizes, int n_in,
                              void* d_out, int out_size, void* d_ws, size_t ws_size,
                              hipStream_t stream) {
    const float* logits = (const float*)d_in[0];   // [8,3,384,384] f32
    const int* targets = (const int*)d_in[1];      // [8,384,384] i32
    float* out = (float*)d_out;                    // scalar f32

    u64* bm = (u64*)d_ws;                                       // 55296 u64
    float* out12 = (float*)(bm + (size_t)BB * CC * NW * WW);    // 18432 floats

    {
        dim3 grid(BB, NW, 4);                                   // 192 blocks
        buildbm<<<grid, WW, 0, stream>>>(targets, (u16*)bm);
    }
    {
        dim3 grid(GROUPS, BB);                                  // 192*8 = 1536 blocks
        edt2<<<grid, WW, 0, stream>>>(bm, logits, out12);
    }
    final_k<<<1, WW, 0, stream>>>(out12, out);
}

// Round 11
// 78.692 us; speedup vs baseline: 1.4220x; 1.0884x over previous
//
#include <hip/hip_runtime.h>

typedef unsigned long long u64;
typedef unsigned short u16;

#define HH 384
#define WW 384
#define BB 8
#define CC 3
#define NMASK (BB*CC)        // 24
#define PLANE (HH*WW)        // 147456
#define NW 6                 // 384 rows = 6 x 64-bit words
#define ROWS_PG 4            // 4 | 64 -> a row group never spans bitmask words
#define GROUPS 96            // 384/4 -> 768 blocks = 3/CU even
#define CHUNK 4              // fallback ring radii per batch
#define INF_F 1.0e6f

// ---------------------------------------------------------------------------
// Algebra: only the 3 per-class bg EDT fields d_c(q)=dist(q,{t==c}) are
// computed. fg_c(q)=dist(q,{t!=c}) = 0 where t(q)!=c, else min of the other
// two d's (dist-to-union = min of dists; bit-exact, sqrt monotone).
// loss = sum_m S_bg/max_bg - S_fg/max_fg  (divide-after-sum; ~1e-7 rel)
// mask non-empty <=> max_bg <= 1000 (real EDT max < 542; empty-set >= 1e6)
//
// Row-EDT: aligned 12-float window [basek, basek+12) ⊇ [j-4, j+4]∩[0,WW) of
// candidates fl((k-j)^2 + g2[k]) — every one is an exact reference candidate
// (diff^2 exact fp32 int, fmaf rounds = fl(fl(diff^2)+g2)). If mn <= 25, all
// |k-j| >= 5 candidates are >= 25 >= mn (fp32 add of nonnegatives >= each
// operand under RN) -> done; else (P ~ (2/3)^69 ~ 0, but handled) serial
// chunked fallback from r=5 with clamped indices (clamped entries duplicate
// true candidates with larger radius term — safe, min unchanged).
//
// Wave reduction: DPP (row_shr 1/2/4/8 + row_bcast 15/31), identity 0 (all
// values >= 0), result in lane 63 — VALU pipe, zero LDS-crossbar traffic.
//
// ws layout:
//   u64   bm[BB][CC][NW][WW]        column seed bitmasks (442368 B)
//   float out12[NMASK][4][GROUPS]   per-(b,c): {Sbg,Sfg,Mbg,Mfg} x rowgroup
// ---------------------------------------------------------------------------

template <int CTRL>
__device__ __forceinline__ float dpp_mov(float v) {
    return __int_as_float(__builtin_amdgcn_update_dpp(
        0, __float_as_int(v), CTRL, 0xf, 0xf, true));
}
__device__ __forceinline__ float wave_sum64(float v) {
    v += dpp_mov<0x111>(v);   // row_shr:1
    v += dpp_mov<0x112>(v);   // row_shr:2
    v += dpp_mov<0x114>(v);   // row_shr:4
    v += dpp_mov<0x118>(v);   // row_shr:8  -> lane15 of each row = row sum
    v += dpp_mov<0x142>(v);   // row_bcast:15 -> lane31 += lane15, lane47+=..., lane63 += lane47? (bcast to next row)
    v += dpp_mov<0x143>(v);   // row_bcast:31 -> lane63 = total
    return v;                 // valid in lane 63 (identity 0 shifts in zeros)
}
__device__ __forceinline__ float wave_max64(float v) {
    v = fmaxf(v, dpp_mov<0x111>(v));
    v = fmaxf(v, dpp_mov<0x112>(v));
    v = fmaxf(v, dpp_mov<0x114>(v));
    v = fmaxf(v, dpp_mov<0x118>(v));
    v = fmaxf(v, dpp_mov<0x142>(v));
    v = fmaxf(v, dpp_mov<0x143>(v));
    return v;                 // valid in lane 63 (identity 0: inputs >= 0)
}

// Grid (BB, NW, 4): thread j builds a 16-bit partial of the 64-row bitmask
// word for its column, all 3 classes (u16 stores, little-endian, no atomics).
__global__ __launch_bounds__(WW) void buildbm(const int* __restrict__ targets,
                                              u16* __restrict__ bm16) {
    int b = blockIdx.x, w = blockIdx.y, q = blockIdx.z;
    int j = threadIdx.x;
    const int* tg = targets + (size_t)b * PLANE + (w * 64 + q * 16) * WW + j;
    unsigned m0 = 0, m1 = 0, m2 = 0;
#pragma unroll
    for (int r = 0; r < 16; ++r) {
        int t = tg[r * WW];
        unsigned bit = 1u << r;
        m0 |= (t == 0) ? bit : 0u;
        m1 |= (t == 1) ? bit : 0u;
        m2 |= (t == 2) ? bit : 0u;
    }
    size_t base = (((size_t)b * CC) * NW + w) * WW + j;          // c = 0
    bm16[base * 4 + q] = (u16)m0;
    bm16[(base + (size_t)NW * WW) * 4 + q] = (u16)m1;
    bm16[(base + 2 * (size_t)NW * WW) * 4 + q] = (u16)m2;
}

// Grid (GROUPS, BB): block = 4 rows x 384 cols, all 3 classes.
__global__ __launch_bounds__(WW) void edt4w(const u64* __restrict__ bm,
                                            const float* __restrict__ logits,
                                            float* __restrict__ out12) {
    __shared__ __align__(16) float g2s[ROWS_PG][CC][WW];   // 18432 B
    __shared__ float red[12][WW / 64];
    int g = blockIdx.x, b = blockIdx.y;
    int j = threadIdx.x;
    int i0 = g * ROWS_PG;
    int w = i0 >> 6;
    int wbase = w << 6;

    u64 word[CC];
    int P[CC], N[CC];
#pragma unroll
    for (int c = 0; c < CC; ++c) {
        u64 wb[NW];
#pragma unroll
        for (int wq = 0; wq < NW; ++wq)
            wb[wq] = bm[(((size_t)b * CC + c) * NW + wq) * WW + j];
        int p = -1, n = -1;
#pragma unroll
        for (int wq = 0; wq < NW; ++wq)
            if (wq < w && wb[wq]) p = wq * 64 + 63 - __builtin_clzll(wb[wq] | 1ull);
#pragma unroll
        for (int wq = NW - 1; wq >= 0; --wq)
            if (wq > w && wb[wq]) n = wq * 64 + (int)__builtin_ctzll(wb[wq] | 0x8000000000000000ull);
        P[c] = p; N[c] = n;
        word[c] = wb[w];
    }

    // Phase A: 4 rows x 3 classes of exact column distances -> LDS.
    u64 lowmask = ((1ull << (i0 & 63)) << 1) - 1ull;    // bits 0..bi
#pragma unroll
    for (int rl = 0; rl < ROWS_PG; ++rl) {
        int i = i0 + rl;
        u64 himask = ~(lowmask >> 1);                   // bits bi..63
#pragma unroll
        for (int c = 0; c < CC; ++c) {
            u64 lo = word[c] & lowmask;
            int last = lo ? (wbase + 63 - __builtin_clzll(lo | 1ull)) : P[c];
            u64 hi = word[c] & himask;
            int next = hi ? (wbase + (int)__builtin_ctzll(hi | 0x8000000000000000ull)) : N[c];
            float fwd = (last >= 0) ? (float)(i - last) : (INF_F + (float)(i + 1));
            float bwd = (next >= 0) ? (float)(next - i) : (INF_F + (float)(HH - i));
            float gc = fminf(fwd, bwd);
            g2s[rl][c][j] = gc * gc;
        }
        lowmask = (lowmask << 1) | 1ull;
    }
    __syncthreads();

    // aligned 12-float window covering [j-4, j+4]
    int basek = (j - 4) & ~3;
    if (basek < 0) basek = 0;
    if (basek > WW - 12) basek = WW - 12;
    float df0 = (float)(basek - j);

    // Phase B: per row, softmax once + 3 window searches (+never-fires fallback).
    float Sb0 = 0.f, Sb1 = 0.f, Sb2 = 0.f, Sf0 = 0.f, Sf1 = 0.f, Sf2 = 0.f;
    float Mb0 = 0.f, Mb1 = 0.f, Mb2 = 0.f, Mf0 = 0.f, Mf1 = 0.f, Mf2 = 0.f;
    const float* lg = logits + ((size_t)b * CC * HH + i0) * WW + j;
#pragma unroll
    for (int rl = 0; rl < ROWS_PG; ++rl) {
        int bi = (i0 + rl) & 63;
        float l0 = lg[rl * WW], l1 = lg[PLANE + rl * WW], l2 = lg[2 * PLANE + rl * WW];
        float mx = fmaxf(l0, fmaxf(l1, l2));
        float x0 = __expf(l0 - mx), x1 = __expf(l1 - mx), x2 = __expf(l2 - mx);
        float rs = __fdividef(1.0f, x0 + x1 + x2);
        float pr0 = x0 * rs, pr1 = x1 * rs, pr2 = x2 * rs;

        float d[CC];
#pragma unroll
        for (int c = 0; c < CC; ++c) {
            const float* g2 = g2s[rl][c];
            // 3 independent b128 loads — one latency wait, no chain
            float4 W0 = *(const float4*)(g2 + basek);
            float4 W1 = *(const float4*)(g2 + basek + 4);
            float4 W2 = *(const float4*)(g2 + basek + 8);
            float df = df0;
            float mn;
            mn =           fmaf(df, df, W0.x);  df += 1.f;
            mn = fminf(mn, fmaf(df, df, W0.y)); df += 1.f;
            mn = fminf(mn, fmaf(df, df, W0.z)); df += 1.f;
            mn = fminf(mn, fmaf(df, df, W0.w)); df += 1.f;
            mn = fminf(mn, fmaf(df, df, W1.x)); df += 1.f;
            mn = fminf(mn, fmaf(df, df, W1.y)); df += 1.f;
            mn = fminf(mn, fmaf(df, df, W1.z)); df += 1.f;
            mn = fminf(mn, fmaf(df, df, W1.w)); df += 1.f;
            mn = fminf(mn, fmaf(df, df, W2.x)); df += 1.f;
            mn = fminf(mn, fmaf(df, df, W2.y)); df += 1.f;
            mn = fminf(mn, fmaf(df, df, W2.z)); df += 1.f;
            mn = fminf(mn, fmaf(df, df, W2.w));
            if (mn > 25.f) {               // radius-4 prune failed (P ~ 0)
                for (int r0 = 5; r0 < WW; r0 += CHUNK) {
                    float r0sq = (float)(r0 * r0);   // exact fp32 integer
                    if (r0sq >= mn) break;
                    float cl[CHUNK], cr[CHUNK];
#pragma unroll
                    for (int u = 0; u < CHUNK; ++u) {
                        int r = r0 + u;
                        int kl = j - r; kl = (kl < 0) ? 0 : kl;
                        int kr = j + r; kr = (kr > WW - 1) ? WW - 1 : kr;
                        cl[u] = g2[kl];
                        cr[u] = g2[kr];
                    }
#pragma unroll
                    for (int u = 0; u < CHUNK; ++u) {
                        float rr = (float)((r0 + u) * (r0 + u));
                        mn = fminf(mn, fminf(rr + cl[u], rr + cr[u]));
                    }
                }
            }
            d[c] = sqrtf(mn);
        }
        // fg_c = (t==c) ? min of other two bg dists : 0
        float f0 = ((word[0] >> bi) & 1ull) ? fminf(d[1], d[2]) : 0.f;
        float f1 = ((word[1] >> bi) & 1ull) ? fminf(d[0], d[2]) : 0.f;
        float f2 = ((word[2] >> bi) & 1ull) ? fminf(d[0], d[1]) : 0.f;

        Sb0 += pr0 * d[0]; Sb1 += pr1 * d[1]; Sb2 += pr2 * d[2];
        Sf0 += pr0 * f0;   Sf1 += pr1 * f1;   Sf2 += pr2 * f2;
        Mb0 = fmaxf(Mb0, d[0]); Mb1 = fmaxf(Mb1, d[1]); Mb2 = fmaxf(Mb2, d[2]);
        Mf0 = fmaxf(Mf0, f0);   Mf1 = fmaxf(Mf1, f1);   Mf2 = fmaxf(Mf2, f2);
    }

    // DPP wave reduction (VALU pipe) -> lane 63; then tiny cross-wave combine.
    float acc[12] = {Sb0, Sf0, Mb0, Mf0, Sb1, Sf1, Mb1, Mf1, Sb2, Sf2, Mb2, Mf2};
    int lane = j & 63, wid = j >> 6;
#pragma unroll
    for (int a = 0; a < 12; ++a) {
        bool ismax = (a & 2) != 0;         // k = a&3: 0,1 sums; 2,3 maxes
        float v = ismax ? wave_max64(acc[a]) : wave_sum64(acc[a]);
        if (lane == 63) red[a][wid] = v;
    }
    __syncthreads();
    if (j < 12) {
        int c = j >> 2, k = j & 3;
        bool ismax = (k & 2) != 0;
        float v = red[j][0];
#pragma unroll
        for (int t = 1; t < WW / 64; ++t)
            v = ismax ? fmaxf(v, red[j][t]) : (v + red[j][t]);
        out12[((size_t)(b * CC + c) * 4 + k) * GROUPS + g] = v;
    }
}

// One block: reduce 24 masks x 4 stats x 96 groups -> scalar loss.
__global__ __launch_bounds__(WW) void final_k(const float* __restrict__ out12,
                                              float* __restrict__ out) {
    __shared__ float contrib[NMASK];
    int t = threadIdx.x;
    int m = t >> 4, l = t & 15;            // 24 masks x 16 lanes
    float sb = 0.f, sf = 0.f, mb = 0.f, mf = 0.f;
    for (int gg = l; gg < GROUPS; gg += 16) {
        const float* p = out12 + (size_t)m * 4 * GROUPS + gg;
        sb += p[0 * GROUPS];
        sf += p[1 * GROUPS];
        mb = fmaxf(mb, p[2 * GROUPS]);
        mf = fmaxf(mf, p[3 * GROUPS]);
    }
#pragma unroll
    for (int off = 8; off > 0; off >>= 1) {
        sb += __shfl_down(sb, off, 16);
        sf += __shfl_down(sf, off, 16);
        mb = fmaxf(mb, __shfl_down(mb, off, 16));
        mf = fmaxf(mf, __shfl_down(mf, off, 16));
    }
    if (l == 0) {
        float cv = 0.f;
        if (mb <= 1000.0f)                 // mask non-empty
            cv = sb / fmaxf(mb, 1e-12f) - sf / fmaxf(mf, 1e-12f);
        contrib[m] = cv;
    }
    __syncthreads();
    if (t == 0) {
        float tot = 0.f;
        for (int mk = 0; mk < NMASK; ++mk) tot += contrib[mk];
        out[0] = tot / (float)((size_t)BB * CC * PLANE);
    }
}

extern "C" void kernel_launch(void* const* d_in, const int* in_sizes, int n_in,
                              void* d_out, int out_size, void* d_ws, size_t ws_size,
                              hipStream_t stream) {
    const float* logits = (const float*)d_in[0];   // [8,3,384,384] f32
    const int* targets = (const int*)d_in[1];      // [8,384,384] i32
    float* out = (float*)d_out;                    // scalar f32

    u64* bm = (u64*)d_ws;                                       // 55296 u64
    float* out12 = (float*)(bm + (size_t)BB * CC * NW * WW);    // 9216 floats

    {
        dim3 grid(BB, NW, 4);                                   // 192 blocks
        buildbm<<<grid, WW, 0, stream>>>(targets, (u16*)bm);
    }
    {
        dim3 grid(GROUPS, BB);                                  // 96*8 = 768 blocks
        edt4w<<<grid, WW, 0, stream>>>(bm, logits, out12);
    }
    final_k<<<1, WW, 0, stream>>>(out12, out);
}